// Round 1
// baseline (805.215 us; speedup 1.0000x reference)
//
#include <hip/hip_runtime.h>
#include <hip/hip_bf16.h>

#define Bdim 128
#define Ddim 2048
#define Mdim 65536
#define Cdim 8192
#define N2   256
#define T_SPCL_INV 20.0f
#define T_TMP_INV  10.0f

typedef __attribute__((ext_vector_type(8))) short  short8;
typedef __attribute__((ext_vector_type(4))) float  floatx4;

// pack two fp32 -> two bf16 (RNE) in one u32
static __device__ __forceinline__ unsigned int pk2bf(float lo, float hi) {
  unsigned int a = __float_as_uint(lo);
  a += 0x7fffu + ((a >> 16) & 1u);
  unsigned int b = __float_as_uint(hi);
  b += 0x7fffu + ((b >> 16) & 1u);
  return (a >> 16) | (b & 0xffff0000u);
}

// ---- normalize inputs rows, emit bf16 x [128][2048] ----
__global__ __launch_bounds__(256) void k_normalize(const float* __restrict__ in,
                                                   unsigned short* __restrict__ xbf) {
  __shared__ float red[4];
  int b = blockIdx.x, t = threadIdx.x;
  const float4* row = (const float4*)(in + (long)b * Ddim);
  float4 v0 = row[t * 2], v1 = row[t * 2 + 1];
  float ss = v0.x*v0.x + v0.y*v0.y + v0.z*v0.z + v0.w*v0.w
           + v1.x*v1.x + v1.y*v1.y + v1.z*v1.z + v1.w*v1.w;
  for (int off = 32; off; off >>= 1) ss += __shfl_down(ss, off);
  if ((t & 63) == 0) red[t >> 6] = ss;
  __syncthreads();
  float rn = rsqrtf(red[0] + red[1] + red[2] + red[3]);
  uint4 o;
  o.x = pk2bf(v0.x * rn, v0.y * rn);
  o.y = pk2bf(v0.z * rn, v0.w * rn);
  o.z = pk2bf(v1.x * rn, v1.y * rn);
  o.w = pk2bf(v1.z * rn, v1.w * rn);
  ((uint4*)(xbf + (long)b * Ddim))[t] = o;
}

// ---- cast feats_aug into f-ordered bf16 [256][2048] ----
__global__ __launch_bounds__(256) void k_castf(const float* __restrict__ fa,
                                               unsigned short* __restrict__ fbf) {
  int j = blockIdx.x, t = threadIdx.x;
  const float4* src = (const float4*)(fa + (long)((j & 127) * 2 + (j >> 7)) * Ddim);
  float4 v0 = src[t * 2], v1 = src[t * 2 + 1];
  uint4 o;
  o.x = pk2bf(v0.x, v0.y); o.y = pk2bf(v0.z, v0.w);
  o.z = pk2bf(v1.x, v1.y); o.w = pk2bf(v1.z, v1.w);
  ((uint4*)(fbf + (long)j * Ddim))[t] = o;
}

// ---- counting sort of memory entries by pseudo-label ----
__global__ void k_count(const int* __restrict__ lab, int* __restrict__ counts) {
  int m = blockIdx.x * 256 + threadIdx.x;
  atomicAdd(&counts[lab[m]], 1);
}

__global__ __launch_bounds__(256) void k_prefix(const int* __restrict__ counts,
                                                int* __restrict__ offs,
                                                int* __restrict__ cursor) {
  __shared__ int lds[256];
  int t = threadIdx.x;
  int base = t * 32;
  int local[32];
  int s = 0;
#pragma unroll
  for (int i = 0; i < 32; ++i) { local[i] = counts[base + i]; s += local[i]; }
  lds[t] = s;
  __syncthreads();
  for (int off = 1; off < 256; off <<= 1) {
    int v = (t >= off) ? lds[t - off] : 0;
    __syncthreads();
    lds[t] += v;
    __syncthreads();
  }
  int run = lds[t] - s;  // exclusive base
#pragma unroll
  for (int i = 0; i < 32; ++i) {
    offs[base + i] = run;
    cursor[base + i] = run;
    run += local[i];
  }
}

__global__ void k_scatter(const int* __restrict__ lab, int* __restrict__ cursor,
                          int* __restrict__ sorted) {
  int m = blockIdx.x * 256 + threadIdx.x;
  int p = atomicAdd(&cursor[lab[m]], 1);
  sorted[p] = m;
}

// ---- main GEMM: sims_T[M][128] = (features @ x^T) / T_SPCL, fp32-in bf16-MFMA ----
__global__ __launch_bounds__(256) void k_gemm(const float* __restrict__ feats,
                                              const unsigned short* __restrict__ xbf,
                                              float* __restrict__ sims) {
  __shared__ __align__(16) unsigned short aT[64 * 40];   // 64 rows x 32 K (+8 pad)
  __shared__ __align__(16) unsigned short xT[128 * 40];  // 128 cols x 32 K (+8 pad)
  int t = threadIdx.x;
  int lane = t & 63, wid = t >> 6;
  long m0 = (long)blockIdx.x * 64;

  // A staging: thread -> (row 0..63, 8-float segment 0..3)
  int arow = t >> 2, aseg = t & 3;
  const float* gA = feats + (m0 + arow) * Ddim + aseg * 8;
  unsigned short* lA = &aT[arow * 40 + aseg * 8];

  // X staging: thread -> (row 0..127, 16-elem half 0..1)
  int xrow = t >> 1, xhalf = t & 1;
  const unsigned short* gX = xbf + (long)xrow * Ddim + xhalf * 16;
  unsigned short* lX = &xT[xrow * 40 + xhalf * 16];

  const unsigned short* aF = &aT[(wid * 16 + (lane & 15)) * 40 + (lane >> 4) * 8];
  int bbase = (lane & 15) * 40 + (lane >> 4) * 8;

  floatx4 zero = {0.f, 0.f, 0.f, 0.f};
  floatx4 acc[8];
#pragma unroll
  for (int i = 0; i < 8; ++i) acc[i] = zero;

  for (int kt = 0; kt < Ddim / 32; ++kt) {
    int k0 = kt * 32;
    float4 f0 = *(const float4*)(gA + k0);
    float4 f1 = *(const float4*)(gA + k0 + 4);
    uint4 x0 = *(const uint4*)(gX + k0);
    uint4 x1 = *(const uint4*)(gX + k0 + 8);
    __syncthreads();
    uint4 pa;
    pa.x = pk2bf(f0.x, f0.y); pa.y = pk2bf(f0.z, f0.w);
    pa.z = pk2bf(f1.x, f1.y); pa.w = pk2bf(f1.z, f1.w);
    *(uint4*)lA = pa;
    *(uint4*)lX = x0;
    *(uint4*)(lX + 8) = x1;
    __syncthreads();
    short8 af = *(const short8*)aF;
#pragma unroll
    for (int nt = 0; nt < 8; ++nt) {
      short8 bf = *(const short8*)&xT[nt * 16 * 40 + bbase];
      acc[nt] = __builtin_amdgcn_mfma_f32_16x16x32_bf16(af, bf, acc[nt], 0, 0, 0);
    }
  }

  long orow = m0 + wid * 16 + (lane >> 4) * 4;
  int ocol = lane & 15;
#pragma unroll
  for (int nt = 0; nt < 8; ++nt) {
#pragma unroll
    for (int r = 0; r < 4; ++r) {
      sims[(orow + r) * Bdim + nt * 16 + ocol] = acc[nt][r] * T_SPCL_INV;
    }
  }
}

// ---- per-class mean + exp (masked): one wave per class ----
__global__ __launch_bounds__(256) void k_classmean(const float* __restrict__ sims,
                                                   const int* __restrict__ counts,
                                                   const int* __restrict__ offs,
                                                   const int* __restrict__ sorted,
                                                   float* __restrict__ exps) {
  int wid = threadIdx.x >> 6, lane = threadIdx.x & 63;
  int c = blockIdx.x * 4 + wid;
  int cnt = counts[c], off = offs[c];
  float sx = 0.f, sy = 0.f;
  for (int i = 0; i < cnt; ++i) {
    int m = sorted[off + i];
    float2 v = ((const float2*)(sims + (long)m * Bdim))[lane];
    sx += v.x; sy += v.y;
  }
  float2 e;
  if (cnt > 0) {
    float ic = (float)cnt;
    e.x = expf(sx / ic);
    e.y = expf(sy / ic);
  } else {
    e.x = 0.f; e.y = 0.f;
  }
  ((float2*)(exps + (long)c * Bdim))[lane] = e;
}

// ---- softmax denominator per b ----
__global__ __launch_bounds__(128) void k_denom(const float* __restrict__ exps,
                                               float* __restrict__ denom) {
  int b = threadIdx.x;
  long c0 = (long)blockIdx.x * 128;
  float s = 0.f;
  for (int i = 0; i < 128; ++i) s += exps[(c0 + i) * Bdim + b];
  atomicAdd(&denom[b], s);
}

// ---- SPCL final loss ----
__global__ __launch_bounds__(128) void k_spcl(const float* __restrict__ exps,
                                              const float* __restrict__ denom,
                                              const int* __restrict__ idx,
                                              const int* __restrict__ mlab,
                                              float* __restrict__ out) {
  __shared__ float red[2];
  int b = threadIdx.x;
  int tc = mlab[idx[b]];
  float p = exps[(long)tc * Bdim + b] / (denom[b] + 1e-6f);
  float l = -logf(p + 1e-6f);
  for (int off = 32; off; off >>= 1) l += __shfl_down(l, off);
  if ((b & 63) == 0) red[b >> 6] = l;
  __syncthreads();
  if (b == 0) atomicAdd(out, (red[0] + red[1]) * (1.0f / Bdim));
}

// ---- logits = f @ f^T via one MFMA tile per wave ----
__global__ __launch_bounds__(256) void k_logits(const unsigned short* __restrict__ fbf,
                                                float* __restrict__ logit) {
  int lane = threadIdx.x & 63, wid = threadIdx.x >> 6;
  int tm = blockIdx.x >> 2;
  int tn = (blockIdx.x & 3) * 4 + wid;
  const unsigned short* pA = fbf + (long)(tm * 16 + (lane & 15)) * Ddim + (lane >> 4) * 8;
  const unsigned short* pB = fbf + (long)(tn * 16 + (lane & 15)) * Ddim + (lane >> 4) * 8;
  floatx4 acc = {0.f, 0.f, 0.f, 0.f};
#pragma unroll 4
  for (int kt = 0; kt < 64; ++kt) {
    short8 a = *(const short8*)(pA + kt * 32);
    short8 b = *(const short8*)(pB + kt * 32);
    acc = __builtin_amdgcn_mfma_f32_16x16x32_bf16(a, b, acc, 0, 0, 0);
  }
  int r0 = tm * 16 + (lane >> 4) * 4;
  int c = tn * 16 + (lane & 15);
#pragma unroll
  for (int r = 0; r < 4; ++r) logit[(r0 + r) * N2 + c] = acc[r];
}

// ---- contrastive per-row masked CE ----
__global__ __launch_bounds__(256) void k_contrast(const float* __restrict__ logit,
                                                  const int* __restrict__ label,
                                                  float* __restrict__ out) {
  __shared__ float red[4];
  int i = blockIdx.x, j = threadIdx.x;
  int lane = j & 63, wid = j >> 6;
  float Lj = logit[i * N2 + j] * T_TMP_INV;
  bool self = (j == i);
  bool pos = (!self) && (label[i & 127] == label[j & 127]);

  float v = self ? -1e30f : Lj;
  for (int off = 32; off; off >>= 1) v = fmaxf(v, __shfl_down(v, off));
  if (lane == 0) red[wid] = v;
  __syncthreads();
  float m = fmaxf(fmaxf(red[0], red[1]), fmaxf(red[2], red[3]));
  __syncthreads();

  float E = self ? 0.f : expf(Lj - m);
  float neg = pos ? 0.f : E;
  for (int off = 32; off; off >>= 1) neg += __shfl_down(neg, off);
  if (lane == 0) red[wid] = neg;
  __syncthreads();
  float neg_sum = red[0] + red[1] + red[2] + red[3];
  __syncthreads();

  float pp = pos ? (logf(E + neg_sum) + m - Lj) : 0.f;
  for (int off = 32; off; off >>= 1) pp += __shfl_down(pp, off);
  if (lane == 0) red[wid] = pp;
  __syncthreads();
  float s_pp = red[0] + red[1] + red[2] + red[3];
  __syncthreads();

  float cw = pos ? 1.f : 0.f;
  for (int off = 32; off; off >>= 1) cw += __shfl_down(cw, off);
  if (lane == 0) red[wid] = cw;
  __syncthreads();
  float s_cnt = red[0] + red[1] + red[2] + red[3];

  if (j == 0) atomicAdd(out, (s_pp / s_cnt) * (1.0f / N2));
}

extern "C" void kernel_launch(void* const* d_in, const int* in_sizes, int n_in,
                              void* d_out, int out_size, void* d_ws, size_t ws_size,
                              hipStream_t stream) {
  const float* inputs     = (const float*)d_in[0];
  const float* feats_aug  = (const float*)d_in[1];
  const float* features   = (const float*)d_in[2];
  const int*   idx        = (const int*)d_in[3];
  const int*   label      = (const int*)d_in[4];
  const int*   mem_labels = (const int*)d_in[5];
  float* out = (float*)d_out;

  char* w = (char*)d_ws;
  auto alloc = [&](size_t bytes) {
    char* p = w;
    w += (bytes + 511) & ~((size_t)511);
    return p;
  };
  unsigned short* xbf    = (unsigned short*)alloc((size_t)Bdim * Ddim * 2);
  unsigned short* fbf    = (unsigned short*)alloc((size_t)N2 * Ddim * 2);
  int*   counts = (int*)alloc(Cdim * 4);
  int*   offs   = (int*)alloc(Cdim * 4);
  int*   cursor = (int*)alloc(Cdim * 4);
  int*   sorted = (int*)alloc(Mdim * 4);
  float* denom  = (float*)alloc(Bdim * 4);
  float* logit  = (float*)alloc(N2 * N2 * 4);
  float* exps   = (float*)alloc((size_t)Cdim * Bdim * 4);
  float* sims   = (float*)alloc((size_t)Mdim * Bdim * 4);

  hipMemsetAsync(counts, 0, Cdim * 4, stream);
  hipMemsetAsync(denom, 0, Bdim * 4, stream);
  hipMemsetAsync(out, 0, (size_t)out_size * sizeof(float), stream);

  k_normalize<<<Bdim, 256, 0, stream>>>(inputs, xbf);
  k_castf<<<N2, 256, 0, stream>>>(feats_aug, fbf);
  k_count<<<Mdim / 256, 256, 0, stream>>>(mem_labels, counts);
  k_prefix<<<1, 256, 0, stream>>>(counts, offs, cursor);
  k_scatter<<<Mdim / 256, 256, 0, stream>>>(mem_labels, cursor, sorted);
  k_gemm<<<Mdim / 64, 256, 0, stream>>>(features, xbf, sims);
  k_classmean<<<Cdim / 4, 256, 0, stream>>>(sims, counts, offs, sorted, exps);
  k_denom<<<Cdim / 128, 128, 0, stream>>>(exps, denom);
  k_spcl<<<1, Bdim, 0, stream>>>(exps, denom, idx, mem_labels, out);
  k_logits<<<64, 256, 0, stream>>>(fbf, logit);
  k_contrast<<<N2, 256, 0, stream>>>(logit, label, out);
}